// Round 1
// baseline (6525.005 us; speedup 1.0000x reference)
//
#include <hip/hip_runtime.h>
#include <math.h>

namespace {
constexpr int NS    = 32000;   // samples per batch row
constexpr int NFFT  = 400;
constexpr int HOP   = 160;
constexpr int NMEL  = 128;
constexpr int NFRQ  = 201;     // NFFT/2 + 1
constexpr int NT    = 201;     // frames: (32400 - 400)/160 + 1
constexpr int TOUT  = 192;
constexpr int MAXW  = 16;      // max nonzero bins per mel filter (true max ~9)
constexpr float SQRT2 = 1.41421356237309515f;
constexpr float TWOPI = 6.28318530717958647692f;
}

__global__ __launch_bounds__(256)
void melpcen_kernel(const float* __restrict__ audio, float* __restrict__ out)
{
  __shared__ float xs[NFFT];          // windowed frame
  __shared__ float win[NFFT];         // hann window
  __shared__ float powr[NFRQ];        // power spectrum of current frame
  __shared__ float melw[MAXW][NMEL];  // sparse mel weights, transposed (bank-friendly)
  __shared__ int   mstart[NMEL];      // first freq bin of each mel filter
  __shared__ float fpts[NMEL + 2];    // mel break frequencies (Hz)

  const int tid = threadIdx.x;
  const int b   = blockIdx.x;

  // ---- Hann window ----
  for (int n = tid; n < NFFT; n += 256) {
    win[n] = 0.5f * (1.0f - cosf(TWOPI * (float)n / (float)NFFT));
  }
  // ---- mel break points (float64 on device, matches numpy) ----
  if (tid < NMEL + 2) {
    double mhi = 2595.0 * log10(1.0 + 8000.0 / 700.0);
    double m   = mhi * (double)tid / (double)(NMEL + 1);
    fpts[tid]  = (float)(700.0 * (pow(10.0, m / 2595.0) - 1.0));
  }
  __syncthreads();
  // ---- sparse mel filterbank: per mel, first bin + up to MAXW weights ----
  if (tid < NMEL) {
    float fl = fpts[tid], fc = fpts[tid + 1], fr = fpts[tid + 2];
    float d0 = fc - fl, d1 = fr - fc;
    int k0 = (int)floorf(fl / 40.0f) + 1;   // first bin strictly above fl
    if (k0 < 0) k0 = 0;
    mstart[tid] = k0;
    for (int j = 0; j < MAXW; ++j) {
      int k = k0 + j;
      float f = 40.0f * (float)k;           // bin center Hz (8000/200 per bin)
      float w = fminf((f - fl) / d0, (fr - f) / d1);
      w = fmaxf(w, 0.0f);
      if (k >= NFRQ) w = 0.0f;
      melw[j][tid] = w;
    }
  }
  __syncthreads();

  // ---- per-bin twiddle step (loop-invariant across frames) ----
  float cf = 1.0f, sf = 0.0f;
  if (tid < NFRQ) {
    float th = TWOPI * (float)tid / (float)NFFT;
    cf = cosf(th); sf = sinf(th);
  }

  // PCEN state + pcen ring (times t, t-1, t-2) live in registers of tid<128
  float M = 0.0f, p0 = 0.0f, p1 = 0.0f, p2 = 0.0f;
  int next_i = 0;
  const float INVS = (float)NT / (float)TOUT;  // 201/192 = inv scale
  const float R    = INVS;                     // antialias triangle radius

  const float* __restrict__ a  = audio + (size_t)b * NS;
  float* __restrict__ ob       = out   + (size_t)b * (TOUT * NMEL);

  for (int t = 0; t < NT; ++t) {
    __syncthreads();
    // ---- stage windowed frame (reflect padding, pad = 200) ----
    for (int n = tid; n < NFFT; n += 256) {
      int g = t * HOP + n - NFFT / 2;
      if (g < 0) g = -g;
      if (g >= NS) g = 2 * NS - 2 - g;
      xs[n] = a[g] * win[n];
    }
    __syncthreads();
    // ---- DFT bin per thread via rotation recurrence (no twiddle table) ----
    if (tid < NFRQ) {
      float c = 1.0f, s = 0.0f, re = 0.0f, im = 0.0f;
      #pragma unroll 8
      for (int n = 0; n < NFFT; ++n) {
        float xv = xs[n];                 // LDS broadcast
        re = fmaf(xv, c, re);
        im = fmaf(xv, s, im);
        float cn = fmaf(cf, c, -(sf * s));
        s = fmaf(cf, s, sf * c);
        c = cn;
      }
      powr[tid] = re * re + im * im;
    }
    __syncthreads();
    // ---- sparse mel + PCEN (thread m = mel bin) ----
    float pc = 0.0f;
    if (tid < NMEL) {
      float mel = 0.0f;
      int k0 = mstart[tid];
      #pragma unroll
      for (int j = 0; j < MAXW; ++j) {
        int k = k0 + j; if (k > NFRQ - 1) k = NFRQ - 1;  // weights are 0 there
        mel = fmaf(melw[j][tid], powr[k], mel);
      }
      M = (t == 0) ? mel : fmaf(0.96f, M, 0.04f * mel);
      float dn = exp2f(0.8f * log2f(1e-8f + M));          // (1e-8 + M)^0.8
      pc = sqrtf(mel / dn + 2.0f) - SQRT2;
    }
    // shift pcen ring (uniform across block)
    p2 = p1; p1 = p0; p0 = pc;
    // ---- streaming antialiased resize: emit outputs whose last tap is t ----
    while (next_i < TOUT) {
      float c = ((float)next_i + 0.5f) * INVS - 0.5f;   // src coord
      int jhi = (int)floorf(c + R);
      if (jhi > NT - 1) jhi = NT - 1;
      if (jhi != t) break;
      int jlo = (int)ceilf(c - R);
      if (jlo < 0) jlo = 0;
      float wsum = 0.0f, val = 0.0f;
      #pragma unroll 3
      for (int j = jlo; j <= jhi; ++j) {
        float w = 1.0f - fabsf((float)j - c) / R;        // tri((j-c)/R)
        w = fmaxf(w, 0.0f);
        wsum += w;
        int d = t - j;                                   // 0,1,2 -> p0,p1,p2
        float pv = (d == 0) ? p0 : ((d == 1) ? p1 : p2);
        val = fmaf(w, pv, val);
      }
      if (tid < NMEL) ob[(size_t)next_i * NMEL + tid] = val / wsum;
      ++next_i;
    }
  }
}

extern "C" void kernel_launch(void* const* d_in, const int* in_sizes, int n_in,
                              void* d_out, int out_size, void* d_ws, size_t ws_size,
                              hipStream_t stream) {
  const float* audio = (const float*)d_in[0];
  float* out = (float*)d_out;
  (void)in_sizes; (void)n_in; (void)out_size; (void)d_ws; (void)ws_size;
  melpcen_kernel<<<2048, 256, 0, stream>>>(audio, out);
}

// Round 3
// 1354.178 us; speedup vs baseline: 4.8184x; 4.8184x over previous
//
#include <hip/hip_runtime.h>
#include <math.h>

typedef __attribute__((ext_vector_type(8))) _Float16 half8;
typedef __attribute__((ext_vector_type(4))) float f32x4;

namespace {
constexpr int NS   = 32000;
constexpr int PAD  = 200;
constexpr int NT   = 201;     // frames
constexpr int TOUT = 192;
constexpr int AUD_ELEMS = 33536;          // fp16 audio elements (u16), covers frag reads
constexpr int PW_COLS   = 202;            // fp32 power row stride (201 bins + 1 pad)
constexpr int BAS_KS = 13, BAS_NT = 28;   // DFT basis: K=416, N=448 (cols 0..401 live)
constexpr int BAS_ELEMS = BAS_KS * BAS_NT * 64 * 8;   // 186368 fp16
constexpr int LDS_BYTES = NT * PW_COLS * 4;           // 162408 B (max phase need)
}

// DFT basis in MFMA B-fragment layout, fp16, window folded in:
//   frag idx = ((ks*28 + nt)*64 + lane)*8 + j
//   k = ks*32 + (lane>>4)*8 + j ; col = nt*16 + (lane&15)
//   col even -> win[k]*cos(2*pi*bin*k/400), odd -> win[k]*sin(...), bin = col/2
__global__ void setup_tables(unsigned short* __restrict__ ws) {
  int idx = blockIdx.x * 256 + threadIdx.x;
  if (idx < BAS_ELEMS) {
    int j = idx & 7, lane = (idx >> 3) & 63, rest = idx >> 9;
    int nt = rest % BAS_NT, ks = rest / BAS_NT;
    int k   = ks * 32 + ((lane >> 4) << 3) + j;
    int col = nt * 16 + (lane & 15);
    float v = 0.f;
    if (k < 400 && col < 402) {
      int bin = col >> 1;
      int mm  = (k * bin) % 400;
      float th = (float)mm * 0.015707963267948967f;    // 2*pi/400
      float tr = (col & 1) ? sinf(th) : cosf(th);
      float wn = 0.5f * (1.0f - cosf((float)k * 0.015707963267948967f));
      v = wn * tr;
    }
    _Float16 h = (_Float16)v;
    ws[idx] = __builtin_bit_cast(unsigned short, h);
  }
}

__global__ __launch_bounds__(512, 2)
void melpcen_main(const float* __restrict__ audio, const unsigned short* __restrict__ ws,
                  float* __restrict__ out)
{
  extern __shared__ unsigned char ldsraw[];
  unsigned short* au = (unsigned short*)ldsraw;   // phase 1-2: fp16 audio [33536]
  float*          pw = (float*)ldsraw;            // phase 3+: power fp32 [201][202], then mel/pcen [201][128]
  const int tid = threadIdx.x;
  const int b   = blockIdx.x;
  const float* __restrict__ ab = audio + (size_t)b * NS;

  // ---- phase 1: audio -> LDS fp16 with reflect pad (pad=200) ----
  for (int i = tid; i < AUD_ELEMS; i += 512) {
    float v = 0.f;
    if (i < NS + 2 * PAD) {
      int pos = i - PAD;
      if (pos < 0) pos = -pos;
      if (pos >= NS) pos = 2 * NS - 2 - pos;
      v = ab[pos];
    }
    _Float16 h = (_Float16)v;
    au[i] = __builtin_bit_cast(unsigned short, h);
  }
  __syncthreads();

  const int w = tid >> 6, lane = tid & 63;
  const int lr = lane & 15, lg = lane >> 4;
  const int mhalf = w >> 2, ngrp = w & 3;   // 2 M-halves x 4 N-groups (7 tiles each)

  // ---- phase 2: DFT via fp16 MFMA. C[frame][col], cols interleaved cos/sin ----
  f32x4 acc[7][7];
  #pragma unroll
  for (int mm = 0; mm < 7; ++mm)
    #pragma unroll
    for (int n = 0; n < 7; ++n) acc[mm][n] = (f32x4){0.f, 0.f, 0.f, 0.f};
  {
    const int laneA = lr * 160 + lg * 8;
    for (int ks = 0; ks < 13; ++ks) {
      half8 Bf[7];
      const unsigned short* bsrc = ws + ((size_t)((ks * 28 + ngrp * 7) * 64 + lane)) * 8;
      #pragma unroll
      for (int n = 0; n < 7; ++n) Bf[n] = *(const half8*)(bsrc + n * 512);
      #pragma unroll
      for (int mm = 0; mm < 7; ++mm) {
        int mt = mhalf * 7 + mm;
        if (mt < 13) {
          half8 Af = *(const half8*)(au + mt * 2560 + ks * 32 + laneA);
          #pragma unroll
          for (int n = 0; n < 7; ++n)
            acc[mm][n] = __builtin_amdgcn_mfma_f32_16x16x32_f16(Af, Bf[n], acc[mm][n], 0, 0, 0);
        }
      }
    }
  }
  __syncthreads();   // all audio reads done; power may now overwrite the region

  // ---- phase 3: power = re^2 + im^2 -> fp32 LDS [201][202] ----
  #pragma unroll
  for (int mm = 0; mm < 7; ++mm) {
    int mt = mhalf * 7 + mm;
    if (mt < 13) {
      #pragma unroll
      for (int n = 0; n < 7; ++n) {
        int gcol = (ngrp * 7 + n) * 16 + lr;
        #pragma unroll
        for (int j = 0; j < 4; ++j) {
          float v = acc[mm][n][j];
          float q = __shfl_xor(v, 1);            // partner col (re<->im)
          int row = mt * 16 + lg * 4 + j;
          if (!(gcol & 1) && gcol < 402 && row < NT)
            pw[row * PW_COLS + (gcol >> 1)] = fmaf(v, v, q * q);
        }
      }
    }
  }
  __syncthreads();

  // ---- phase 4: sparse mel projection, fp32 VALU; results held in regs ----
  const int m = tid & 127, c = tid >> 7;
  float melv[51];
  {
    float mhi = 2595.0f * log10f(1.0f + 8000.0f / 700.0f);
    float l2e = 3.3219280948873623f;   // log2(10)
    float ml = mhi * (float)m       / 129.0f;
    float mc = mhi * (float)(m + 1) / 129.0f;
    float mr = mhi * (float)(m + 2) / 129.0f;
    float fl = 700.0f * (exp2f(ml / 2595.0f * l2e) - 1.0f);
    float fc = 700.0f * (exp2f(mc / 2595.0f * l2e) - 1.0f);
    float fr = 700.0f * (exp2f(mr / 2595.0f * l2e) - 1.0f);
    int k0 = (int)floorf(fl / 40.0f) + 1;
    if (k0 < 0) k0 = 0;
    float wt[10];
    #pragma unroll
    for (int j = 0; j < 10; ++j) {
      int k = k0 + j;
      float f = 40.0f * (float)k;
      float wv = fminf((f - fl) / (fc - fl), (fr - f) / (fr - fc));
      wv = fmaxf(wv, 0.0f);
      if (k > 200) wv = 0.0f;
      wt[j] = wv;
    }
    #pragma unroll
    for (int i = 0; i < 51; ++i) {
      int t = c + 4 * i;
      float s = 0.f;
      if (t < NT) {
        const float* prow = pw + t * PW_COLS;
        #pragma unroll
        for (int j = 0; j < 10; ++j) {
          int k = k0 + j; if (k > 200) k = 200;   // wt[j]==0 there
          s = fmaf(wt[j], prow[k], s);
        }
      }
      melv[i] = s;
    }
  }
  __syncthreads();
  // write mel fp32 [201][128] over the power region
  float* melp = pw;
  #pragma unroll
  for (int i = 0; i < 51; ++i) {
    int t = c + 4 * i;
    if (t < NT) melp[t * 128 + m] = melv[i];
  }
  __syncthreads();

  // ---- phase 5: PCEN fp32, 4-chunk parallel linear scan, in-place ----
  {
    const int t0  = (c == 0) ? 0 : (51 + 50 * (c - 1));
    const int len = (c == 0) ? 51 : 50;
    float M = 0.f;
    for (int t = t0; t < t0 + len; ++t) {
      float e = melp[t * 128 + m];
      M = (t == 0) ? e : fmaf(0.96f, M, 0.04f * e);
    }
    float* carry = pw + 25728;   // [4][128] fp32
    float* minb  = pw + 26240;   // [4][128] fp32
    carry[c * 128 + m] = M;
    __syncthreads();
    if (c == 0) {
      float a50 = exp2f(50.0f * log2f(0.96f));   // 0.96^50
      float m1 = carry[m];
      float m2 = fmaf(a50, m1, carry[128 + m]);
      float m3 = fmaf(a50, m2, carry[256 + m]);
      minb[128 + m] = m1; minb[256 + m] = m2; minb[384 + m] = m3;
    }
    __syncthreads();
    float Min = (c == 0) ? 0.f : minb[c * 128 + m];
    float wf = 1.f, Mloc = 0.f;
    for (int t = t0; t < t0 + len; ++t) {
      float e = melp[t * 128 + m];
      Mloc = (t == 0) ? e : fmaf(0.96f, Mloc, 0.04f * e);
      wf *= 0.96f;
      float Mt = fmaf(wf, Min, Mloc);
      float dn = exp2f(0.8f * log2f(1e-8f + Mt));     // (1e-8+M)^0.8
      float pc = sqrtf(e / dn + 2.0f) - 1.41421356237309515f;
      melp[t * 128 + m] = pc;   // in-place (own cell, read above)
    }
  }
  __syncthreads();

  // ---- phase 6: antialiased linear resize 201 -> 192 (time axis), fp32 store ----
  {
    float* __restrict__ ob = out + (size_t)b * (TOUT * 128);
    const float INVS = 201.0f / 192.0f;   // 67/64, exact
    for (int i = c; i < TOUT; i += 4) {
      float ct = ((float)i + 0.5f) * INVS - 0.5f;
      int jlo = (int)ceilf(ct - INVS);
      int jhi = (int)floorf(ct + INVS);
      if (jlo < 0) jlo = 0;
      if (jhi > NT - 1) jhi = NT - 1;
      float wsum = 0.f, val = 0.f;
      for (int j = jlo; j <= jhi; ++j) {
        float wv = 1.0f - fabsf((float)j - ct) / INVS;
        if (wv > 0.f) { wsum += wv; val = fmaf(wv, melp[j * 128 + m], val); }
      }
      ob[(size_t)i * 128 + m] = val / wsum;
    }
  }
}

extern "C" void kernel_launch(void* const* d_in, const int* in_sizes, int n_in,
                              void* d_out, int out_size, void* d_ws, size_t ws_size,
                              hipStream_t stream) {
  (void)in_sizes; (void)n_in; (void)out_size; (void)ws_size;
  unsigned short* ws = (unsigned short*)d_ws;
  setup_tables<<<(BAS_ELEMS + 255) / 256, 256, 0, stream>>>(ws);
  melpcen_main<<<2048, 512, LDS_BYTES, stream>>>((const float*)d_in[0], ws, (float*)d_out);
}

// Round 4
// 756.351 us; speedup vs baseline: 8.6270x; 1.7904x over previous
//
#include <hip/hip_runtime.h>
#include <math.h>

typedef __attribute__((ext_vector_type(8))) _Float16 half8;
typedef __attribute__((ext_vector_type(4))) float f32x4;

namespace {
constexpr int NS   = 32000;
constexpr int PAD  = 200;
constexpr int NT   = 201;     // frames
constexpr int TOUT = 192;
constexpr int AUD_ELEMS = 33536;          // fp16 audio region (u16 elems)
constexpr int PW_STRIDE = 232;            // power row stride (u16) = 464 B -> odd 16B-slot stride
constexpr int PW_ROWS   = 208;
constexpr int PW_OFF    = AUD_ELEMS;      // power region starts after audio
constexpr int BAS_KS = 13, BAS_NT = 28;   // DFT basis: K=416, N=448 (cols 0..401 live)
constexpr int FB_KS  = 7,  FB_NT  = 8;    // mel fb: K=224, N=128
constexpr int BAS_ELEMS = BAS_KS * BAS_NT * 64 * 8;   // 186368
constexpr int FB_ELEMS  = FB_KS  * FB_NT  * 64 * 8;   // 28672
constexpr int LDS_BYTES = (AUD_ELEMS + PW_ROWS * PW_STRIDE) * 2;  // 163584 <= 163840
}

// audio-LDS XOR swizzle: breaks the 320B frame-stride 8-way bank conflict.
// XORs element bits [4:3] with bits [8:7]; preserves aligned-8 contiguity.
__device__ __forceinline__ int swz(int e) { return e ^ (((e >> 7) & 3) << 3); }

// ws tables, fp16, MFMA B-fragment layout:
//  [0, BAS_ELEMS): DFT basis frag[ks][nt][lane][j]: k=ks*32+(lane>>4)*8+j, col=nt*16+(lane&15)
//                  col even -> win[k]*cos(2*pi*bin*k/400), odd -> sin; bin=col/2
//  [BAS_ELEMS, +FB_ELEMS): mel fb frag[ks][nt][lane][j]: k=freq bin, col=mel
__global__ void setup_tables(unsigned short* __restrict__ ws) {
  int idx = blockIdx.x * 256 + threadIdx.x;
  if (idx < BAS_ELEMS) {
    int j = idx & 7, lane = (idx >> 3) & 63, rest = idx >> 9;
    int nt = rest % BAS_NT, ks = rest / BAS_NT;
    int k   = ks * 32 + ((lane >> 4) << 3) + j;
    int col = nt * 16 + (lane & 15);
    float v = 0.f;
    if (k < 400 && col < 402) {
      int bin = col >> 1;
      int mm  = (k * bin) % 400;
      float th = (float)mm * 0.015707963267948967f;    // 2*pi/400
      float tr = (col & 1) ? sinf(th) : cosf(th);
      float wn = 0.5f * (1.0f - cosf((float)k * 0.015707963267948967f));
      v = wn * tr;
    }
    _Float16 h = (_Float16)v;
    ws[idx] = __builtin_bit_cast(unsigned short, h);
  } else if (idx < BAS_ELEMS + FB_ELEMS) {
    int i2 = idx - BAS_ELEMS;
    int j = i2 & 7, lane = (i2 >> 3) & 63, rest = i2 >> 9;
    int nt = rest % FB_NT, ks = rest / FB_NT;
    int k   = ks * 32 + ((lane >> 4) << 3) + j;        // freq bin
    int mel = nt * 16 + (lane & 15);
    float v = 0.f;
    if (k <= 200) {
      double mhi = 2595.0 * log10(1.0 + 8000.0 / 700.0);
      double ml = mhi * (double)mel / 129.0;
      double mc = mhi * (double)(mel + 1) / 129.0;
      double mr = mhi * (double)(mel + 2) / 129.0;
      double fl = 700.0 * (pow(10.0, ml / 2595.0) - 1.0);
      double fc = 700.0 * (pow(10.0, mc / 2595.0) - 1.0);
      double fr = 700.0 * (pow(10.0, mr / 2595.0) - 1.0);
      double f  = 40.0 * (double)k;
      double wv = fmin((f - fl) / (fc - fl), (fr - f) / (fr - fc));
      v = (float)fmax(0.0, wv);
    }
    _Float16 h = (_Float16)v;
    ws[idx] = __builtin_bit_cast(unsigned short, h);
  }
}

__global__ __launch_bounds__(512) __attribute__((amdgpu_waves_per_eu(2)))
void melpcen_main(const float* __restrict__ audio, const unsigned short* __restrict__ ws,
                  float* __restrict__ out)
{
  extern __shared__ unsigned char ldsraw[];
  unsigned short* au   = (unsigned short*)ldsraw;       // fp16 audio (swizzled), dead after P4... P2
  unsigned short* pw16 = (unsigned short*)ldsraw + PW_OFF;  // fp16 power [208][232]
  float*          melp = (float*)ldsraw;                // P5+: mel/pcen fp32 [201][128]
  const int tid = threadIdx.x;
  const int b   = blockIdx.x;
  const float* __restrict__ ab = audio + (size_t)b * NS;

  // ---- phase 1: zero power region; audio -> LDS fp16 (reflect pad, swizzled) ----
  for (int i = tid; i < PW_ROWS * PW_STRIDE; i += 512) pw16[i] = 0;
  for (int i = tid; i < AUD_ELEMS; i += 512) {
    float v = 0.f;
    if (i < NS + 2 * PAD) {
      int pos = i - PAD;
      if (pos < 0) pos = -pos;
      if (pos >= NS) pos = 2 * NS - 2 - pos;
      v = ab[pos];
    }
    _Float16 h = (_Float16)v;
    au[swz(i)] = __builtin_bit_cast(unsigned short, h);
  }
  __syncthreads();

  const int w = tid >> 6, lane = tid & 63;
  const int lr = lane & 15, lg = lane >> 4;
  const int mhalf = w >> 2, ngrp = w & 3;   // 2 M-halves x 4 N-groups (7 tiles each)

  // ---- phase 2: DFT via fp16 MFMA. C[frame][col], cols interleaved cos/sin ----
  f32x4 acc[7][7];
  #pragma unroll
  for (int mm = 0; mm < 7; ++mm)
    #pragma unroll
    for (int n = 0; n < 7; ++n) acc[mm][n] = (f32x4){0.f, 0.f, 0.f, 0.f};
  {
    const int laneA = lr * 160 + lg * 8;
    for (int ks = 0; ks < 13; ++ks) {
      half8 Bf[7];
      const unsigned short* bsrc = ws + ((size_t)((ks * 28 + ngrp * 7) * 64 + lane)) * 8;
      #pragma unroll
      for (int n = 0; n < 7; ++n) Bf[n] = *(const half8*)(bsrc + n * 512);
      #pragma unroll
      for (int mm = 0; mm < 7; ++mm) {
        int mt = mhalf * 7 + mm;
        if (mt < 13) {
          int e = mt * 2560 + ks * 32 + laneA;
          half8 Af = *(const half8*)(au + swz(e));
          #pragma unroll
          for (int n = 0; n < 7; ++n)
            acc[mm][n] = __builtin_amdgcn_mfma_f32_16x16x32_f16(Af, Bf[n], acc[mm][n], 0, 0, 0);
        }
      }
    }
  }
  __syncthreads();   // audio reads done

  // ---- phase 3: power = re^2+im^2 -> fp16 LDS [row][bin], stride 232 ----
  #pragma unroll
  for (int mm = 0; mm < 7; ++mm) {
    int mt = mhalf * 7 + mm;
    if (mt < 13) {
      #pragma unroll
      for (int n = 0; n < 7; ++n) {
        int gcol = (ngrp * 7 + n) * 16 + lr;
        #pragma unroll
        for (int j = 0; j < 4; ++j) {
          float v = acc[mm][n][j];
          float q = __shfl_xor(v, 1);            // partner col (re<->im)
          int row = mt * 16 + lg * 4 + j;
          if (!(gcol & 1) && gcol < 402 && row < NT) {
            _Float16 h = (_Float16)fmaf(v, v, q * q);
            pw16[row * PW_STRIDE + (gcol >> 1)] = __builtin_bit_cast(unsigned short, h);
          }
        }
      }
    }
  }
  __syncthreads();

  // ---- phase 4: mel = power x fb via fp16 MFMA (fp32 accum); hold in regs ----
  float melv[13][4];
  {
    half8 Fb[7];
    const unsigned short* fsrc = ws + BAS_ELEMS + (size_t)w * 512 + (size_t)lane * 8;
    #pragma unroll
    for (int ks = 0; ks < 7; ++ks) Fb[ks] = *(const half8*)(fsrc + ks * 4096);
    for (int mt = 0; mt < 13; ++mt) {
      f32x4 a2 = (f32x4){0.f, 0.f, 0.f, 0.f};
      const unsigned short* psrc = pw16 + (mt * 16 + lr) * PW_STRIDE + lg * 8;
      #pragma unroll
      for (int ks = 0; ks < 7; ++ks)
        a2 = __builtin_amdgcn_mfma_f32_16x16x32_f16(*(const half8*)(psrc + ks * 32), Fb[ks], a2, 0, 0, 0);
      #pragma unroll
      for (int j = 0; j < 4; ++j) melv[mt][j] = a2[j];
    }
  }
  __syncthreads();   // all power reads done; LDS is now free for fp32 mel
  {
    const int melcol = w * 16 + lr;
    #pragma unroll
    for (int mt = 0; mt < 13; ++mt) {
      #pragma unroll
      for (int j = 0; j < 4; ++j) {
        int row = mt * 16 + lg * 4 + j;
        if (row < NT) melp[row * 128 + melcol] = melv[mt][j];
      }
    }
  }
  __syncthreads();

  // ---- phase 5: PCEN fp32, 4-chunk parallel linear scan, in-place ----
  const int m = tid & 127, c = tid >> 7;
  {
    const int t0  = (c == 0) ? 0 : (51 + 50 * (c - 1));
    const int len = (c == 0) ? 51 : 50;
    float M = 0.f;
    for (int t = t0; t < t0 + len; ++t) {
      float e = melp[t * 128 + m];
      M = (t == 0) ? e : fmaf(0.96f, M, 0.04f * e);
    }
    float* carry = melp + 25728;   // [4][128] fp32 (past mel rows)
    float* minb  = melp + 26240;   // [4][128] fp32
    carry[c * 128 + m] = M;
    __syncthreads();
    if (c == 0) {
      float a50 = exp2f(50.0f * log2f(0.96f));   // 0.96^50
      float m1 = carry[m];
      float m2 = fmaf(a50, m1, carry[128 + m]);
      float m3 = fmaf(a50, m2, carry[256 + m]);
      minb[128 + m] = m1; minb[256 + m] = m2; minb[384 + m] = m3;
    }
    __syncthreads();
    float Min = (c == 0) ? 0.f : minb[c * 128 + m];
    float wf = 1.f, Mloc = 0.f;
    for (int t = t0; t < t0 + len; ++t) {
      float e = melp[t * 128 + m];
      Mloc = (t == 0) ? e : fmaf(0.96f, Mloc, 0.04f * e);
      wf *= 0.96f;
      float Mt = fmaf(wf, Min, Mloc);
      float dn = exp2f(0.8f * log2f(1e-8f + Mt));     // (1e-8+M)^0.8
      float pc = sqrtf(e / dn + 2.0f) - 1.41421356237309515f;
      melp[t * 128 + m] = pc;   // in-place
    }
  }
  __syncthreads();

  // ---- phase 6: antialiased linear resize 201 -> 192 (time), fp32 store ----
  {
    float* __restrict__ ob = out + (size_t)b * (TOUT * 128);
    const float INVS = 201.0f / 192.0f;
    for (int i = c; i < TOUT; i += 4) {
      float ct = ((float)i + 0.5f) * INVS - 0.5f;
      int jlo = (int)ceilf(ct - INVS);
      int jhi = (int)floorf(ct + INVS);
      if (jlo < 0) jlo = 0;
      if (jhi > NT - 1) jhi = NT - 1;
      float wsum = 0.f, val = 0.f;
      for (int j = jlo; j <= jhi; ++j) {
        float wv = 1.0f - fabsf((float)j - ct) / INVS;
        if (wv > 0.f) { wsum += wv; val = fmaf(wv, melp[j * 128 + m], val); }
      }
      ob[(size_t)i * 128 + m] = val / wsum;
    }
  }
}

extern "C" void kernel_launch(void* const* d_in, const int* in_sizes, int n_in,
                              void* d_out, int out_size, void* d_ws, size_t ws_size,
                              hipStream_t stream) {
  (void)in_sizes; (void)n_in; (void)out_size; (void)ws_size;
  unsigned short* ws = (unsigned short*)d_ws;
  setup_tables<<<(BAS_ELEMS + FB_ELEMS + 255) / 256, 256, 0, stream>>>(ws);
  melpcen_main<<<2048, 512, LDS_BYTES, stream>>>((const float*)d_in[0], ws, (float*)d_out);
}